// Round 11
// baseline (441.879 us; speedup 1.0000x reference)
//
#include <hip/hip_runtime.h>
#include <hip/hip_bf16.h>

#define NB 4
#define TT 2048
#define CC 2048
#define HH 16
#define DD 128

typedef short bvec8 __attribute__((ext_vector_type(8)));
typedef float fvec4 __attribute__((ext_vector_type(4)));

__device__ __forceinline__ void gload16(const void* g, void* l) {
  __builtin_amdgcn_global_load_lds(
      (__attribute__((address_space(1))) void*)g,
      (__attribute__((address_space(3))) void*)l, 16, 0, 0);
}

__device__ __forceinline__ unsigned short f2bf(float f) {
  union { float f; unsigned int u; } x; x.f = f;
  unsigned int u = x.u;
  return (unsigned short)((u + 0x7FFFu + ((u >> 16) & 1u)) >> 16);
}

__device__ __forceinline__ fvec4 mfma16(bvec8 a, bvec8 b, fvec4 c) {
  return __builtin_amdgcn_mfma_f32_16x16x32_bf16(a, b, c, 0, 0, 0);
}

// scale * log2(e), folded into K at the QKV epilogue
#define KSC (0.08838834764831845f * 1.4426950408889634f)

// ---------------- merged prep: cvt x -> bf16, transpose w_attn, transpose w_proj ----------------
__global__ __launch_bounds__(256) void k_prep(const float* __restrict__ x,
                                              unsigned short* __restrict__ xb,
                                              const float* __restrict__ wa,
                                              unsigned short* __restrict__ wat,
                                              const float* __restrict__ wp,
                                              unsigned short* __restrict__ wpt) {
  __shared__ unsigned short tile[64][65];
  int bid = blockIdx.x;
  int t = threadIdx.x;
  if (bid < 16384) {
    int i = bid * 256 + t;
    float4 v = ((const float4*)x)[i];
    ushort4 o;
    o.x = f2bf(v.x); o.y = f2bf(v.y); o.z = f2bf(v.z); o.w = f2bf(v.w);
    ((ushort4*)xb)[i] = o;
    return;
  }
  const float* in; unsigned short* out; int R, Cn, bx, by;
  int b2 = bid - 16384;
  if (b2 < 3072) {
    in = wa; out = wat; R = 2048; Cn = 6144; bx = b2 % 96; by = b2 / 96;
  } else {
    int b3 = b2 - 3072;
    in = wp; out = wpt; R = 2048; Cn = 2048; bx = b3 % 32; by = b3 / 32;
  }
  int tC = bx * 64, tR = by * 64;
  int rw = t >> 4, c4 = (t & 15) * 4;
#pragma unroll
  for (int i = 0; i < 4; i++) {
    int row = rw + i * 16;
    float4 v = *(const float4*)&in[(size_t)(tR + row) * Cn + tC + c4];
    tile[row][c4 + 0] = f2bf(v.x);
    tile[row][c4 + 1] = f2bf(v.y);
    tile[row][c4 + 2] = f2bf(v.z);
    tile[row][c4 + 3] = f2bf(v.w);
  }
  __syncthreads();
#pragma unroll
  for (int i = 0; i < 4; i++) {
    int rr = rw + i * 16;                   // out-row within tile (Cn-dim)
    ushort4 o;
    o.x = tile[c4 + 0][rr];
    o.y = tile[c4 + 1][rr];
    o.z = tile[c4 + 2][rr];
    o.w = tile[c4 + 3][rr];
    *(ushort4*)&out[(size_t)(tC + rr) * R + tR + c4] = o;
  }
}

// ============ 256x256 GEMM, BK=64, 8 waves (round-8 measured-best schedule) ============
template <int EPI>
__global__ __launch_bounds__(512, 2) void k_gemm8(
    const unsigned short* __restrict__ A,
    const unsigned short* __restrict__ Bt,
    const float* __restrict__ bias,
    unsigned short* __restrict__ qk,   // EPI=0
    unsigned short* __restrict__ vt,   // EPI=0
    float* __restrict__ out) {         // EPI=1
  const int K = CC;
  const int nt = K / 64;               // 32 K-tiles
  __shared__ unsigned short sm[2][32768];

  int tid = threadIdx.x;
  int wid = tid >> 6, ln = tid & 63, gl = ln >> 4, lo = ln & 15;
  int wr = wid >> 2, wc = wid & 3;     // 2 (M) x 4 (N) waves

  // n-major XCD chunking (measured-best r7)
  unsigned gx = gridDim.x, gy = gridDim.y;   // gx = N-tiles, gy = M-tiles
  unsigned orig = blockIdx.y * gx + blockIdx.x;
  unsigned cpx = (gx * gy) >> 3;
  unsigned wg2 = (orig & 7) * cpx + (orig >> 3);
  int n0 = (int)(wg2 / gy) * 256;
  int m0 = (int)(wg2 % gy) * 256;

  auto stageA = [&](int buf, int half, int kt) {
#pragma unroll
    for (int j = 0; j < 2; j++) {
      int c = j * 512 + tid;
      int r = c >> 3;
      int kc = (c & 7) ^ (r & 7);
      gload16(A + (size_t)(m0 + half * 128 + r) * K + kt * 64 + kc * 8,
              &sm[buf][(size_t)(half * 1024 + c) * 8]);
    }
  };
  auto stageB = [&](int buf, int half, int kt) {
#pragma unroll
    for (int j = 0; j < 2; j++) {
      int c = j * 512 + tid;
      int r = c >> 3;
      int kc = (c & 7) ^ (r & 7);
      gload16(Bt + (size_t)(n0 + half * 128 + r) * K + kt * 64 + kc * 8,
              &sm[buf][16384 + (size_t)(half * 1024 + c) * 8]);
    }
  };

#define AFRAG(buf, mi, ks) \
  (*(const bvec8*)&sm[buf][(((wr * 128 + (mi) * 16 + lo) * 8) + ((((ks) * 4 + gl)) ^ (lo & 7))) * 8])
#define BFRAG(buf, nj, ks) \
  (*(const bvec8*)&sm[buf][16384 + (((wc * 64 + (nj) * 16 + lo) * 8) + ((((ks) * 4 + gl)) ^ (lo & 7))) * 8])

  fvec4 acc[8][4];
  fvec4 zero = {0.f, 0.f, 0.f, 0.f};
#pragma unroll
  for (int i = 0; i < 8; i++)
#pragma unroll
    for (int j = 0; j < 4; j++) acc[i][j] = zero;

  // prologue: tile0 A+B, tile1 A (12 loads; vmcnt(4) at t=0 drains first 8)
  stageA(0, 0, 0); stageA(0, 1, 0); stageB(0, 0, 0); stageB(0, 1, 0);
  stageA(1, 0, 1); stageA(1, 1, 1);

  for (int t = 0; t < nt; t++) {
    int cur = t & 1;
    bvec8 a0[4], a1[4], a2[4], a3[4], b0[4], b1[4];

    // --- tile start: buf[cur] fully landed when only the newest 4 loads remain
    if (t + 1 < nt) {
      asm volatile("s_waitcnt vmcnt(4)" ::: "memory");
    } else {
      asm volatile("s_waitcnt vmcnt(0)" ::: "memory");
    }
    __builtin_amdgcn_sched_barrier(0);
    __builtin_amdgcn_s_barrier();
    __builtin_amdgcn_sched_barrier(0);

    // issue the bulk of the tile's LDS reads + next-tile B staging up front
#pragma unroll
    for (int mi = 0; mi < 4; mi++) a0[mi] = AFRAG(cur, mi, 0);
#pragma unroll
    for (int nj = 0; nj < 4; nj++) b0[nj] = BFRAG(cur, nj, 0);
#pragma unroll
    for (int mi = 0; mi < 4; mi++) a1[mi] = AFRAG(cur, mi + 4, 0);
#pragma unroll
    for (int mi = 0; mi < 4; mi++) a2[mi] = AFRAG(cur, mi, 1);
#pragma unroll
    for (int nj = 0; nj < 4; nj++) b1[nj] = BFRAG(cur, nj, 1);
    if (t + 1 < nt) { stageB(cur ^ 1, 0, t + 1); stageB(cur ^ 1, 1, t + 1); }
    __builtin_amdgcn_sched_barrier(0);

    // q1: a0 x b0
    __builtin_amdgcn_s_setprio(1);
#pragma unroll
    for (int mi = 0; mi < 4; mi++)
#pragma unroll
      for (int nj = 0; nj < 4; nj++) acc[mi][nj] = mfma16(a0[mi], b0[nj], acc[mi][nj]);
    __builtin_amdgcn_s_setprio(0);

    // late-issue the last A subtile
#pragma unroll
    for (int mi = 0; mi < 4; mi++) a3[mi] = AFRAG(cur, mi + 4, 1);
    __builtin_amdgcn_sched_barrier(0);

    // q2: a1 x b0
    __builtin_amdgcn_s_setprio(1);
#pragma unroll
    for (int mi = 0; mi < 4; mi++)
#pragma unroll
      for (int nj = 0; nj < 4; nj++) acc[mi + 4][nj] = mfma16(a1[mi], b0[nj], acc[mi + 4][nj]);
    __builtin_amdgcn_s_setprio(0);

    // q3: a2 x b1
    __builtin_amdgcn_s_setprio(1);
#pragma unroll
    for (int mi = 0; mi < 4; mi++)
#pragma unroll
      for (int nj = 0; nj < 4; nj++) acc[mi][nj] = mfma16(a2[mi], b1[nj], acc[mi][nj]);
    __builtin_amdgcn_s_setprio(0);

    // all LDS reads of buf[cur] done -> barrier -> restage A into buf[cur] for t+2
    asm volatile("s_waitcnt lgkmcnt(0)" ::: "memory");
    __builtin_amdgcn_sched_barrier(0);
    __builtin_amdgcn_s_barrier();
    if (t + 2 < nt) { stageA(cur, 0, t + 2); stageA(cur, 1, t + 2); }

    // q4: a3 x b1
    __builtin_amdgcn_s_setprio(1);
#pragma unroll
    for (int mi = 0; mi < 4; mi++)
#pragma unroll
      for (int nj = 0; nj < 4; nj++) acc[mi + 4][nj] = mfma16(a3[mi], b1[nj], acc[mi + 4][nj]);
    __builtin_amdgcn_s_setprio(0);
  }

  // ---------------- epilogue ----------------
  if (EPI == 0) {
    int s = n0 >> 11;                    // block-constant: Q / K / V block
    if (s < 2) {
      // LDS-transpose epilogue: full-line coalesced Q/K writes.
      asm volatile("s_waitcnt lgkmcnt(0)" ::: "memory");
      __syncthreads();
      unsigned short* se = (unsigned short*)sm;   // [256][256] ushort = 128 KB
      float mulv = (s == 1) ? KSC : 1.0f;
#pragma unroll
      for (int nj = 0; nj < 4; nj++) {
        int coln = wc * 64 + nj * 16 + lo;
        float bn = bias[n0 + coln];
#pragma unroll
        for (int mi = 0; mi < 8; mi++) {
          int rowbase = wr * 128 + mi * 16 + gl * 4;
#pragma unroll
          for (int r = 0; r < 4; r++) {
            int row = rowbase + r;
            int colsw = coln ^ (((row >> 2) & 7) << 3);   // chunk-XOR, bank-spread
            se[row * 256 + colsw] = f2bf((acc[mi][nj][r] + bn) * mulv);
          }
        }
      }
      __syncthreads();
#pragma unroll
      for (int k = 0; k < 16; k++) {
        int c = k * 512 + tid;
        int row = c >> 5, cpos = c & 31;
        int cposw = cpos ^ ((row >> 2) & 7);
        bvec8 v = *(const bvec8*)&se[row * 256 + cposw * 8];
        int mb = m0 + row;
        int b = mb >> 11, t0 = mb & 2047;
        int col = cpos * 8;
        int hh = ((n0 + col) >> 7) & 15;
        int d = col & 127;
        *(bvec8*)&qk[((((size_t)s * NB + b) * HH + hh) * TT + t0) * DD + d] = v;
      }
    } else {
      // V block: vt[b][h][t/8][d][8]
#pragma unroll
      for (int nj = 0; nj < 4; nj++) {
        int n = n0 + wc * 64 + nj * 16 + lo;
        float bn = bias[n];
        int hh = (n >> 7) & 15, d = n & 127;
#pragma unroll
        for (int mi = 0; mi < 8; mi++) {
          int mb = m0 + wr * 128 + mi * 16 + gl * 4;
          int b = mb >> 11, t0 = mb & 2047;
          size_t base = ((((size_t)b * HH + hh) * (TT / 8) + (t0 >> 3)) * DD + d) * 8 + (t0 & 7);
          ushort4 o;
          o.x = f2bf(acc[mi][nj][0] + bn);
          o.y = f2bf(acc[mi][nj][1] + bn);
          o.z = f2bf(acc[mi][nj][2] + bn);
          o.w = f2bf(acc[mi][nj][3] + bn);
          *(ushort4*)&vt[base] = o;
        }
      }
    }
  } else {
#pragma unroll
    for (int nj = 0; nj < 4; nj++) {
      int n = n0 + wc * 64 + nj * 16 + lo;
      float bn = bias[n];
#pragma unroll
      for (int mi = 0; mi < 8; mi++) {
        int m = m0 + wr * 128 + mi * 16 + gl * 4;
#pragma unroll
        for (int r = 0; r < 4; r++) out[(size_t)(m + r) * CC + n] = acc[mi][nj][r] + bn;
      }
    }
  }
#undef AFRAG
#undef BFRAG
}

// ---------------- flash attention: 128 q-rows/block, 32 q-rows/wave, split K/V waits ----------------
__global__ __launch_bounds__(256, 2) void k_attn(
    const unsigned short* __restrict__ qk,   // [2][B][H][T][D], K pre-scaled
    const unsigned short* __restrict__ vt,   // [B][H][T/8][D][8]
    unsigned short* __restrict__ yb) {       // [B][T][C]
  __shared__ unsigned short Ks[2][8192];     // [kk][d] chunks, XOR-swizzled
  __shared__ unsigned short Vs[2][8192];     // [ck][d] chunks, linear
  __shared__ unsigned short Ps[4][2048];     // per-wave P: [2 mf][16][64], chunk-swizzled
  int tid = threadIdx.x, wid = tid >> 6, ln = tid & 63;
  int gl = ln >> 4, lo = ln & 15;
  int qp = blockIdx.x & 7;                   // pair index 0..7 (128-row q-tiles)
  int bh = blockIdx.x >> 3;
  int b = bh >> 4, h = bh & 15;
  const unsigned short* Q  = qk + (((size_t)b * HH + h) * TT) * DD;
  const unsigned short* Kg = qk + ((((size_t)NB + b) * HH + h) * TT) * DD;
  const unsigned short* Vg = vt + (((size_t)b * HH + h) * (TT / 8)) * DD * 8;
  fvec4 zero = {0.f, 0.f, 0.f, 0.f};

  // K first (8 loads), then V (8 loads) — FIFO split-wait depends on this order
  auto stageK = [&](int buf, int it) {
    int k0 = it * 64;
#pragma unroll
    for (int j = 0; j < 4; j++) {
      int c = j * 256 + tid;
      int r = c >> 4, cc = c & 15;
      gload16(Kg + (size_t)(k0 + r) * DD + ((cc ^ (r & 7)) * 8), &Ks[buf][(j * 256 + wid * 64) * 8]);
    }
  };
  auto stageV = [&](int buf, int it) {
    int k0 = it * 64;
#pragma unroll
    for (int j = 0; j < 4; j++) {
      int c = j * 256 + tid;
      int cc = c >> 7, d = c & 127;
      gload16(Vg + ((size_t)(k0 / 8 + cc) * DD + d) * 8, &Vs[buf][(j * 256 + wid * 64) * 8]);
    }
  };

  for (int pass = 0; pass < 2; pass++) {
    int qt = pass ? (15 - qp) : qp;          // combined work = 34 tiles, all blocks equal
    int q0w = qt * 128 + wid * 32;

    bvec8 qf0[4], qf1[4];
#pragma unroll
    for (int ks = 0; ks < 4; ks++) {
      qf0[ks] = *(const bvec8*)(Q + (size_t)(q0w + lo) * DD + ks * 32 + gl * 8);
      qf1[ks] = *(const bvec8*)(Q + (size_t)(q0w + 16 + lo) * DD + ks * 32 + gl * 8);
    }

    fvec4 oacc0[8], oacc1[8];
#pragma unroll
    for (int i = 0; i < 8; i++) { oacc0[i] = zero; oacc1[i] = zero; }
    float mr0[4] = {-1e30f, -1e30f, -1e30f, -1e30f};
    float mr1[4] = {-1e30f, -1e30f, -1e30f, -1e30f};
    float lr0[4] = {0.f, 0.f, 0.f, 0.f};
    float lr1[4] = {0.f, 0.f, 0.f, 0.f};

    int ntiles = 2 * qt + 2;
    stageK(0, 0); stageV(0, 0);
    asm volatile("s_waitcnt vmcnt(8)" ::: "memory");  // K(0) landed; V(0) may fly
    __builtin_amdgcn_sched_barrier(0);
    __builtin_amdgcn_s_barrier();
    __builtin_amdgcn_sched_barrier(0);

    for (int it = 0; it < ntiles; it++) {
      int cur = it & 1;
      int k0 = it * 64;
      bool more = (it + 1 < ntiles);
      // wave-level causal skip: this wave's 32 q-rows all masked for this KV tile
      bool active = (k0 <= q0w + 31);
      if (more) { stageK(cur ^ 1, it + 1); stageV(cur ^ 1, it + 1); }

      if (active) {
        // S = Q K^T: 32 MFMAs sharing 16 K-frag reads
        fvec4 sa0[4], sa1[4];
        __builtin_amdgcn_s_setprio(1);
#pragma unroll
        for (int fn = 0; fn < 4; fn++) {
          fvec4 s0 = zero, s1 = zero;
#pragma unroll
          for (int ks = 0; ks < 4; ks++) {
            int r = fn * 16 + lo;
            int cd = ks * 4 + gl;
            bvec8 kf = *(const bvec8*)&Ks[cur][(r * 16 + (cd ^ (r & 7))) * 8];
            s0 = mfma16(qf0[ks], kf, s0);
            s1 = mfma16(qf1[ks], kf, s1);
          }
          sa0[fn] = s0; sa1[fn] = s1;
        }
        __builtin_amdgcn_s_setprio(0);

        // merged softmax for both 16-row groups: one defer-max branch
        float p0[4][4], p1[4][4], mx0[4], mx1[4];
        bool dm0 = (k0 + 63) > q0w;
        bool dm1 = (k0 + 63) > (q0w + 16);
#pragma unroll
        for (int r = 0; r < 4; r++) {
          float m0v = -1e30f, m1v = -1e30f;
#pragma unroll
          for (int fn = 0; fn < 4; fn++) {
            int kkg = k0 + fn * 16 + lo;
            float v0 = (!dm0 || kkg <= (q0w + gl * 4 + r)) ? sa0[fn][r] : -1e30f;
            float v1 = (!dm1 || kkg <= (q0w + 16 + gl * 4 + r)) ? sa1[fn][r] : -1e30f;
            p0[fn][r] = v0; m0v = fmaxf(m0v, v0);
            p1[fn][r] = v1; m1v = fmaxf(m1v, v1);
          }
          mx0[r] = m0v; mx1[r] = m1v;
        }
        bool g = (mx0[0] > mr0[0] + 8.f) || (mx0[1] > mr0[1] + 8.f) ||
                 (mx0[2] > mr0[2] + 8.f) || (mx0[3] > mr0[3] + 8.f) ||
                 (mx1[0] > mr1[0] + 8.f) || (mx1[1] > mr1[1] + 8.f) ||
                 (mx1[2] > mr1[2] + 8.f) || (mx1[3] > mr1[3] + 8.f);
        if (__any(g)) {
#pragma unroll
          for (int r = 0; r < 4; r++) {
            float m0v = mx0[r], m1v = mx1[r];
#pragma unroll
            for (int dlt = 1; dlt < 16; dlt <<= 1) {
              m0v = fmaxf(m0v, __shfl_xor(m0v, dlt));
              m1v = fmaxf(m1v, __shfl_xor(m1v, dlt));
            }
            float n0v = fmaxf(mr0[r], m0v), n1v = fmaxf(mr1[r], m1v);
            float c0 = exp2f(mr0[r] - n0v), c1 = exp2f(mr1[r] - n1v);
            mr0[r] = n0v; mr1[r] = n1v;
            lr0[r] *= c0; lr1[r] *= c1;
#pragma unroll
            for (int fd = 0; fd < 8; fd++) { oacc0[fd][r] *= c0; oacc1[fd][r] *= c1; }
          }
        }
#pragma unroll
        for (int r = 0; r < 4; r++)
#pragma unroll
          for (int fn = 0; fn < 4; fn++) {
            float pv0 = exp2f(p0[fn][r] - mr0[r]);
            float pv1 = exp2f(p1[fn][r] - mr1[r]);
            p0[fn][r] = pv0; lr0[r] += pv0;
            p1[fn][r] = pv1; lr1[r] += pv1;
          }
#pragma unroll
        for (int fn = 0; fn < 4; fn++)
#pragma unroll
          for (int r = 0; r < 4; r++) {
            int qr = gl * 4 + r;
            int kc = fn * 16 + lo;
            int off = (qr * 8 + ((kc >> 3) ^ (qr & 7))) * 8 + (kc & 7);
            Ps[wid][off] = f2bf(p0[fn][r]);
            Ps[wid][1024 + off] = f2bf(p1[fn][r]);
          }
      }

      // pre-PV: V(cur) landed when only the 16 newer loads (next tile's K+V) remain
      if (more) {
        asm volatile("s_waitcnt vmcnt(16)" ::: "memory");
      } else {
        asm volatile("s_waitcnt vmcnt(0)" ::: "memory");
      }
      __builtin_amdgcn_sched_barrier(0);
      __builtin_amdgcn_s_barrier();
      __builtin_amdgcn_sched_barrier(0);

      if (active) {
        // O += P V: 32 MFMAs sharing 16 V-frag reads
        __builtin_amdgcn_s_setprio(1);
#pragma unroll
        for (int ks2 = 0; ks2 < 2; ks2++) {
          bvec8 pf0 = *(const bvec8*)&Ps[wid][(lo * 8 + ((ks2 * 4 + gl) ^ (lo & 7))) * 8];
          bvec8 pf1 = *(const bvec8*)&Ps[wid][1024 + (lo * 8 + ((ks2 * 4 + gl) ^ (lo & 7))) * 8];
#pragma unroll
          for (int fd = 0; fd < 8; fd++) {
            bvec8 vf = *(const bvec8*)&Vs[cur][((ks2 * 4 + gl) * 128 + fd * 16 + lo) * 8];
            oacc0[fd] = mfma16(pf0, vf, oacc0[fd]);
            oacc1[fd] = mfma16(pf1, vf, oacc1[fd]);
          }
        }
        __builtin_amdgcn_s_setprio(0);
      }

      // end-of-tile: K(it+1) landed when only the 8 newer V-loads remain
      if (more) {
        asm volatile("s_waitcnt vmcnt(8)" ::: "memory");
      } else {
        asm volatile("s_waitcnt vmcnt(0)" ::: "memory");
      }
      __builtin_amdgcn_sched_barrier(0);
      __builtin_amdgcn_s_barrier();
      __builtin_amdgcn_sched_barrier(0);
    }

    // epilogue
#pragma unroll
    for (int r = 0; r < 4; r++) {
      float l0 = lr0[r], l1 = lr1[r];
#pragma unroll
      for (int dlt = 1; dlt < 16; dlt <<= 1) {
        l0 += __shfl_xor(l0, dlt);
        l1 += __shfl_xor(l1, dlt);
      }
      int qrow0 = q0w + gl * 4 + r;
      int qrow1 = q0w + 16 + gl * 4 + r;
      float inv0 = 1.f / l0, inv1 = 1.f / l1;
#pragma unroll
      for (int fd = 0; fd < 8; fd++) {
        int d = fd * 16 + lo;
        yb[((size_t)b * TT + qrow0) * CC + h * DD + d] = f2bf(oacc0[fd][r] * inv0);
        yb[((size_t)b * TT + qrow1) * CC + h * DD + d] = f2bf(oacc1[fd][r] * inv1);
      }
    }
  }
}

extern "C" void kernel_launch(void* const* d_in, const int* in_sizes, int n_in,
                              void* d_out, int out_size, void* d_ws, size_t ws_size,
                              hipStream_t stream) {
  const float* x      = (const float*)d_in[0];
  const float* w_attn = (const float*)d_in[1];
  const float* b_attn = (const float*)d_in[2];
  const float* w_proj = (const float*)d_in[3];
  const float* b_proj = (const float*)d_in[4];
  float* out = (float*)d_out;

  char* ws = (char*)d_ws;
  unsigned short* xb    = (unsigned short*)(ws);                         // 32 MB
  unsigned short* wab_t = (unsigned short*)(ws + 33554432);              // 24 MB
  unsigned short* wpb_t = (unsigned short*)(ws + 58720256);              // 8 MB
  unsigned short* qkws  = (unsigned short*)(ws + 67108864);              // 64 MB
  unsigned short* vtws  = (unsigned short*)(ws + 134217728);             // 32 MB
  unsigned short* ybws  = (unsigned short*)(ws + 167772160);             // 32 MB

  hipLaunchKernelGGL(k_prep, dim3(16384 + 3072 + 1024), dim3(256), 0, stream,
                     x, xb, w_attn, wab_t, w_proj, wpb_t);
  hipLaunchKernelGGL((k_gemm8<0>), dim3(24, 32), dim3(512), 0, stream,
                     xb, wab_t, b_attn, qkws, vtws, (float*)nullptr);
  hipLaunchKernelGGL(k_attn, dim3(512), dim3(256), 0, stream, qkws, vtws, ybws);
  hipLaunchKernelGGL((k_gemm8<1>), dim3(8, 32), dim3(512), 0, stream,
                     ybws, wpb_t, b_proj, (unsigned short*)nullptr, (unsigned short*)nullptr, out);
}

// Round 12
// 430.115 us; speedup vs baseline: 1.0273x; 1.0273x over previous
//
#include <hip/hip_runtime.h>
#include <hip/hip_bf16.h>

#define NB 4
#define TT 2048
#define CC 2048
#define HH 16
#define DD 128

typedef short bvec8 __attribute__((ext_vector_type(8)));
typedef float fvec4 __attribute__((ext_vector_type(4)));

__device__ __forceinline__ void gload16(const void* g, void* l) {
  __builtin_amdgcn_global_load_lds(
      (__attribute__((address_space(1))) void*)g,
      (__attribute__((address_space(3))) void*)l, 16, 0, 0);
}

__device__ __forceinline__ unsigned short f2bf(float f) {
  union { float f; unsigned int u; } x; x.f = f;
  unsigned int u = x.u;
  return (unsigned short)((u + 0x7FFFu + ((u >> 16) & 1u)) >> 16);
}

__device__ __forceinline__ fvec4 mfma16(bvec8 a, bvec8 b, fvec4 c) {
  return __builtin_amdgcn_mfma_f32_16x16x32_bf16(a, b, c, 0, 0, 0);
}

// scale * log2(e), folded into K at the QKV epilogue
#define KSC (0.08838834764831845f * 1.4426950408889634f)

// ---------------- merged prep: cvt x -> bf16, transpose w_attn, transpose w_proj ----------------
__global__ __launch_bounds__(256) void k_prep(const float* __restrict__ x,
                                              unsigned short* __restrict__ xb,
                                              const float* __restrict__ wa,
                                              unsigned short* __restrict__ wat,
                                              const float* __restrict__ wp,
                                              unsigned short* __restrict__ wpt) {
  __shared__ unsigned short tile[64][65];
  int bid = blockIdx.x;
  int t = threadIdx.x;
  if (bid < 16384) {
    int i = bid * 256 + t;
    float4 v = ((const float4*)x)[i];
    ushort4 o;
    o.x = f2bf(v.x); o.y = f2bf(v.y); o.z = f2bf(v.z); o.w = f2bf(v.w);
    ((ushort4*)xb)[i] = o;
    return;
  }
  const float* in; unsigned short* out; int R, Cn, bx, by;
  int b2 = bid - 16384;
  if (b2 < 3072) {
    in = wa; out = wat; R = 2048; Cn = 6144; bx = b2 % 96; by = b2 / 96;
  } else {
    int b3 = b2 - 3072;
    in = wp; out = wpt; R = 2048; Cn = 2048; bx = b3 % 32; by = b3 / 32;
  }
  int tC = bx * 64, tR = by * 64;
  int rw = t >> 4, c4 = (t & 15) * 4;
#pragma unroll
  for (int i = 0; i < 4; i++) {
    int row = rw + i * 16;
    float4 v = *(const float4*)&in[(size_t)(tR + row) * Cn + tC + c4];
    tile[row][c4 + 0] = f2bf(v.x);
    tile[row][c4 + 1] = f2bf(v.y);
    tile[row][c4 + 2] = f2bf(v.z);
    tile[row][c4 + 3] = f2bf(v.w);
  }
  __syncthreads();
#pragma unroll
  for (int i = 0; i < 4; i++) {
    int rr = rw + i * 16;                   // out-row within tile (Cn-dim)
    ushort4 o;
    o.x = tile[c4 + 0][rr];
    o.y = tile[c4 + 1][rr];
    o.z = tile[c4 + 2][rr];
    o.w = tile[c4 + 3][rr];
    *(ushort4*)&out[(size_t)(tC + rr) * R + tR + c4] = o;
  }
}

// ============ 256x256 GEMM, BK=64, 8 waves (round-8 measured-best schedule) ============
template <int EPI>
__global__ __launch_bounds__(512, 2) void k_gemm8(
    const unsigned short* __restrict__ A,
    const unsigned short* __restrict__ Bt,
    const float* __restrict__ bias,
    unsigned short* __restrict__ qk,   // EPI=0
    unsigned short* __restrict__ vt,   // EPI=0
    float* __restrict__ out) {         // EPI=1
  const int K = CC;
  const int nt = K / 64;               // 32 K-tiles
  __shared__ unsigned short sm[2][32768];

  int tid = threadIdx.x;
  int wid = tid >> 6, ln = tid & 63, gl = ln >> 4, lo = ln & 15;
  int wr = wid >> 2, wc = wid & 3;     // 2 (M) x 4 (N) waves

  // n-major XCD chunking (measured-best r7)
  unsigned gx = gridDim.x, gy = gridDim.y;   // gx = N-tiles, gy = M-tiles
  unsigned orig = blockIdx.y * gx + blockIdx.x;
  unsigned cpx = (gx * gy) >> 3;
  unsigned wg2 = (orig & 7) * cpx + (orig >> 3);
  int n0 = (int)(wg2 / gy) * 256;
  int m0 = (int)(wg2 % gy) * 256;

  auto stageA = [&](int buf, int half, int kt) {
#pragma unroll
    for (int j = 0; j < 2; j++) {
      int c = j * 512 + tid;
      int r = c >> 3;
      int kc = (c & 7) ^ (r & 7);
      gload16(A + (size_t)(m0 + half * 128 + r) * K + kt * 64 + kc * 8,
              &sm[buf][(size_t)(half * 1024 + c) * 8]);
    }
  };
  auto stageB = [&](int buf, int half, int kt) {
#pragma unroll
    for (int j = 0; j < 2; j++) {
      int c = j * 512 + tid;
      int r = c >> 3;
      int kc = (c & 7) ^ (r & 7);
      gload16(Bt + (size_t)(n0 + half * 128 + r) * K + kt * 64 + kc * 8,
              &sm[buf][16384 + (size_t)(half * 1024 + c) * 8]);
    }
  };

#define AFRAG(buf, mi, ks) \
  (*(const bvec8*)&sm[buf][(((wr * 128 + (mi) * 16 + lo) * 8) + ((((ks) * 4 + gl)) ^ (lo & 7))) * 8])
#define BFRAG(buf, nj, ks) \
  (*(const bvec8*)&sm[buf][16384 + (((wc * 64 + (nj) * 16 + lo) * 8) + ((((ks) * 4 + gl)) ^ (lo & 7))) * 8])

  fvec4 acc[8][4];
  fvec4 zero = {0.f, 0.f, 0.f, 0.f};
#pragma unroll
  for (int i = 0; i < 8; i++)
#pragma unroll
    for (int j = 0; j < 4; j++) acc[i][j] = zero;

  // prologue: tile0 A+B, tile1 A (12 loads; vmcnt(4) at t=0 drains first 8)
  stageA(0, 0, 0); stageA(0, 1, 0); stageB(0, 0, 0); stageB(0, 1, 0);
  stageA(1, 0, 1); stageA(1, 1, 1);

  for (int t = 0; t < nt; t++) {
    int cur = t & 1;
    bvec8 a0[4], a1[4], a2[4], a3[4], b0[4], b1[4];

    // --- tile start: buf[cur] fully landed when only the newest 4 loads remain
    if (t + 1 < nt) {
      asm volatile("s_waitcnt vmcnt(4)" ::: "memory");
    } else {
      asm volatile("s_waitcnt vmcnt(0)" ::: "memory");
    }
    __builtin_amdgcn_sched_barrier(0);
    __builtin_amdgcn_s_barrier();
    __builtin_amdgcn_sched_barrier(0);

    // issue the bulk of the tile's LDS reads + next-tile B staging up front
#pragma unroll
    for (int mi = 0; mi < 4; mi++) a0[mi] = AFRAG(cur, mi, 0);
#pragma unroll
    for (int nj = 0; nj < 4; nj++) b0[nj] = BFRAG(cur, nj, 0);
#pragma unroll
    for (int mi = 0; mi < 4; mi++) a1[mi] = AFRAG(cur, mi + 4, 0);
#pragma unroll
    for (int mi = 0; mi < 4; mi++) a2[mi] = AFRAG(cur, mi, 1);
#pragma unroll
    for (int nj = 0; nj < 4; nj++) b1[nj] = BFRAG(cur, nj, 1);
    if (t + 1 < nt) { stageB(cur ^ 1, 0, t + 1); stageB(cur ^ 1, 1, t + 1); }
    __builtin_amdgcn_sched_barrier(0);

    // q1: a0 x b0
    __builtin_amdgcn_s_setprio(1);
#pragma unroll
    for (int mi = 0; mi < 4; mi++)
#pragma unroll
      for (int nj = 0; nj < 4; nj++) acc[mi][nj] = mfma16(a0[mi], b0[nj], acc[mi][nj]);
    __builtin_amdgcn_s_setprio(0);

    // late-issue the last A subtile
#pragma unroll
    for (int mi = 0; mi < 4; mi++) a3[mi] = AFRAG(cur, mi + 4, 1);
    __builtin_amdgcn_sched_barrier(0);

    // q2: a1 x b0
    __builtin_amdgcn_s_setprio(1);
#pragma unroll
    for (int mi = 0; mi < 4; mi++)
#pragma unroll
      for (int nj = 0; nj < 4; nj++) acc[mi + 4][nj] = mfma16(a1[mi], b0[nj], acc[mi + 4][nj]);
    __builtin_amdgcn_s_setprio(0);

    // q3: a2 x b1
    __builtin_amdgcn_s_setprio(1);
#pragma unroll
    for (int mi = 0; mi < 4; mi++)
#pragma unroll
      for (int nj = 0; nj < 4; nj++) acc[mi][nj] = mfma16(a2[mi], b1[nj], acc[mi][nj]);
    __builtin_amdgcn_s_setprio(0);

    // all LDS reads of buf[cur] done -> barrier -> restage A into buf[cur] for t+2
    asm volatile("s_waitcnt lgkmcnt(0)" ::: "memory");
    __builtin_amdgcn_sched_barrier(0);
    __builtin_amdgcn_s_barrier();
    if (t + 2 < nt) { stageA(cur, 0, t + 2); stageA(cur, 1, t + 2); }

    // q4: a3 x b1
    __builtin_amdgcn_s_setprio(1);
#pragma unroll
    for (int mi = 0; mi < 4; mi++)
#pragma unroll
      for (int nj = 0; nj < 4; nj++) acc[mi + 4][nj] = mfma16(a3[mi], b1[nj], acc[mi + 4][nj]);
    __builtin_amdgcn_s_setprio(0);
  }

  // ---------------- epilogue ----------------
  if (EPI == 0) {
    int s = n0 >> 11;                    // block-constant: Q / K / V block
    if (s < 2) {
      // LDS-transpose epilogue: full-line coalesced Q/K writes.
      asm volatile("s_waitcnt lgkmcnt(0)" ::: "memory");
      __syncthreads();
      unsigned short* se = (unsigned short*)sm;   // [256][256] ushort = 128 KB
      float mulv = (s == 1) ? KSC : 1.0f;
#pragma unroll
      for (int nj = 0; nj < 4; nj++) {
        int coln = wc * 64 + nj * 16 + lo;
        float bn = bias[n0 + coln];
#pragma unroll
        for (int mi = 0; mi < 8; mi++) {
          int rowbase = wr * 128 + mi * 16 + gl * 4;
#pragma unroll
          for (int r = 0; r < 4; r++) {
            int row = rowbase + r;
            int colsw = coln ^ (((row >> 2) & 7) << 3);   // chunk-XOR, bank-spread
            se[row * 256 + colsw] = f2bf((acc[mi][nj][r] + bn) * mulv);
          }
        }
      }
      __syncthreads();
#pragma unroll
      for (int k = 0; k < 16; k++) {
        int c = k * 512 + tid;
        int row = c >> 5, cpos = c & 31;
        int cposw = cpos ^ ((row >> 2) & 7);
        bvec8 v = *(const bvec8*)&se[row * 256 + cposw * 8];
        int mb = m0 + row;
        int b = mb >> 11, t0 = mb & 2047;
        int col = cpos * 8;
        int hh = ((n0 + col) >> 7) & 15;
        int d = col & 127;
        *(bvec8*)&qk[((((size_t)s * NB + b) * HH + hh) * TT + t0) * DD + d] = v;
      }
    } else {
      // V block: vt[b][h][t/8][d][8]
#pragma unroll
      for (int nj = 0; nj < 4; nj++) {
        int n = n0 + wc * 64 + nj * 16 + lo;
        float bn = bias[n];
        int hh = (n >> 7) & 15, d = n & 127;
#pragma unroll
        for (int mi = 0; mi < 8; mi++) {
          int mb = m0 + wr * 128 + mi * 16 + gl * 4;
          int b = mb >> 11, t0 = mb & 2047;
          size_t base = ((((size_t)b * HH + hh) * (TT / 8) + (t0 >> 3)) * DD + d) * 8 + (t0 & 7);
          ushort4 o;
          o.x = f2bf(acc[mi][nj][0] + bn);
          o.y = f2bf(acc[mi][nj][1] + bn);
          o.z = f2bf(acc[mi][nj][2] + bn);
          o.w = f2bf(acc[mi][nj][3] + bn);
          *(ushort4*)&vt[base] = o;
        }
      }
    }
  } else {
#pragma unroll
    for (int nj = 0; nj < 4; nj++) {
      int n = n0 + wc * 64 + nj * 16 + lo;
      float bn = bias[n];
#pragma unroll
      for (int mi = 0; mi < 8; mi++) {
        int m = m0 + wr * 128 + mi * 16 + gl * 4;
#pragma unroll
        for (int r = 0; r < 4; r++) out[(size_t)(m + r) * CC + n] = acc[mi][nj][r] + bn;
      }
    }
  }
#undef AFRAG
#undef BFRAG
}

// ---------------- flash attention: 128 q-rows/block, 32 q-rows/wave, split K/V waits ----------------
// (r10 measured-best version: sequential per-group smax lambda, wave-level causal skip)
__global__ __launch_bounds__(256, 2) void k_attn(
    const unsigned short* __restrict__ qk,   // [2][B][H][T][D], K pre-scaled
    const unsigned short* __restrict__ vt,   // [B][H][T/8][D][8]
    unsigned short* __restrict__ yb) {       // [B][T][C]
  __shared__ unsigned short Ks[2][8192];     // [kk][d] chunks, XOR-swizzled
  __shared__ unsigned short Vs[2][8192];     // [ck][d] chunks, linear
  __shared__ unsigned short Ps[4][2048];     // per-wave P: [2 mf][16][64], chunk-swizzled
  int tid = threadIdx.x, wid = tid >> 6, ln = tid & 63;
  int gl = ln >> 4, lo = ln & 15;
  int qp = blockIdx.x & 7;                   // pair index 0..7 (128-row q-tiles)
  int bh = blockIdx.x >> 3;
  int b = bh >> 4, h = bh & 15;
  const unsigned short* Q  = qk + (((size_t)b * HH + h) * TT) * DD;
  const unsigned short* Kg = qk + ((((size_t)NB + b) * HH + h) * TT) * DD;
  const unsigned short* Vg = vt + (((size_t)b * HH + h) * (TT / 8)) * DD * 8;
  fvec4 zero = {0.f, 0.f, 0.f, 0.f};

  // K first (8 loads), then V (8 loads) — FIFO split-wait depends on this order
  auto stageK = [&](int buf, int it) {
    int k0 = it * 64;
#pragma unroll
    for (int j = 0; j < 4; j++) {
      int c = j * 256 + tid;
      int r = c >> 4, cc = c & 15;
      gload16(Kg + (size_t)(k0 + r) * DD + ((cc ^ (r & 7)) * 8), &Ks[buf][(j * 256 + wid * 64) * 8]);
    }
  };
  auto stageV = [&](int buf, int it) {
    int k0 = it * 64;
#pragma unroll
    for (int j = 0; j < 4; j++) {
      int c = j * 256 + tid;
      int cc = c >> 7, d = c & 127;
      gload16(Vg + ((size_t)(k0 / 8 + cc) * DD + d) * 8, &Vs[buf][(j * 256 + wid * 64) * 8]);
    }
  };

  // per-16-row-group softmax + P write (mf selected by q0m/psoff)
  auto smax = [&](fvec4 (&sa)[4], float (&mr)[4], float (&lr)[4], fvec4 (&oa)[8],
                  int q0m, int k0, bool domask, int psoff) {
    float p[4][4], mxl[4];
#pragma unroll
    for (int r = 0; r < 4; r++) {
      int qrow = q0m + gl * 4 + r;
      float m = -1e30f;
      if (domask) {
#pragma unroll
        for (int fn = 0; fn < 4; fn++) {
          int kkg = k0 + fn * 16 + lo;
          float v = (kkg <= qrow) ? sa[fn][r] : -1e30f;
          p[fn][r] = v; m = fmaxf(m, v);
        }
      } else {
#pragma unroll
        for (int fn = 0; fn < 4; fn++) {
          float v = sa[fn][r];
          p[fn][r] = v; m = fmaxf(m, v);
        }
      }
      mxl[r] = m;
    }
    bool c = (mxl[0] > mr[0] + 8.f) || (mxl[1] > mr[1] + 8.f) ||
             (mxl[2] > mr[2] + 8.f) || (mxl[3] > mr[3] + 8.f);
    if (__any(c)) {
#pragma unroll
      for (int r = 0; r < 4; r++) {
        float m = mxl[r];
#pragma unroll
        for (int dlt = 1; dlt < 16; dlt <<= 1) m = fmaxf(m, __shfl_xor(m, dlt));
        float mnew = fmaxf(mr[r], m);
        float corr = exp2f(mr[r] - mnew);
        mr[r] = mnew; lr[r] *= corr;
#pragma unroll
        for (int fd = 0; fd < 8; fd++) oa[fd][r] *= corr;
      }
    }
#pragma unroll
    for (int r = 0; r < 4; r++)
#pragma unroll
      for (int fn = 0; fn < 4; fn++) {
        float pv = exp2f(p[fn][r] - mr[r]);
        p[fn][r] = pv; lr[r] += pv;
      }
#pragma unroll
    for (int fn = 0; fn < 4; fn++)
#pragma unroll
      for (int r = 0; r < 4; r++) {
        int qr = gl * 4 + r;
        int kc = fn * 16 + lo;
        Ps[wid][psoff + (qr * 8 + ((kc >> 3) ^ (qr & 7))) * 8 + (kc & 7)] = f2bf(p[fn][r]);
      }
  };

  for (int pass = 0; pass < 2; pass++) {
    int qt = pass ? (15 - qp) : qp;          // combined work = 34 tiles, all blocks equal
    int q0w = qt * 128 + wid * 32;

    bvec8 qf0[4], qf1[4];
#pragma unroll
    for (int ks = 0; ks < 4; ks++) {
      qf0[ks] = *(const bvec8*)(Q + (size_t)(q0w + lo) * DD + ks * 32 + gl * 8);
      qf1[ks] = *(const bvec8*)(Q + (size_t)(q0w + 16 + lo) * DD + ks * 32 + gl * 8);
    }

    fvec4 oacc0[8], oacc1[8];
#pragma unroll
    for (int i = 0; i < 8; i++) { oacc0[i] = zero; oacc1[i] = zero; }
    float mr0[4] = {-1e30f, -1e30f, -1e30f, -1e30f};
    float mr1[4] = {-1e30f, -1e30f, -1e30f, -1e30f};
    float lr0[4] = {0.f, 0.f, 0.f, 0.f};
    float lr1[4] = {0.f, 0.f, 0.f, 0.f};

    int ntiles = 2 * qt + 2;
    stageK(0, 0); stageV(0, 0);
    asm volatile("s_waitcnt vmcnt(8)" ::: "memory");  // K(0) landed; V(0) may fly
    __builtin_amdgcn_sched_barrier(0);
    __builtin_amdgcn_s_barrier();
    __builtin_amdgcn_sched_barrier(0);

    for (int it = 0; it < ntiles; it++) {
      int cur = it & 1;
      int k0 = it * 64;
      bool more = (it + 1 < ntiles);
      // wave-level causal skip: this wave's 32 q-rows all masked for this KV tile
      bool active = (k0 <= q0w + 31);
      if (more) { stageK(cur ^ 1, it + 1); stageV(cur ^ 1, it + 1); }

      if (active) {
        // S = Q K^T: 32 MFMAs sharing 16 K-frag reads
        fvec4 sa0[4], sa1[4];
        __builtin_amdgcn_s_setprio(1);
#pragma unroll
        for (int fn = 0; fn < 4; fn++) {
          fvec4 s0 = zero, s1 = zero;
#pragma unroll
          for (int ks = 0; ks < 4; ks++) {
            int r = fn * 16 + lo;
            int cd = ks * 4 + gl;
            bvec8 kf = *(const bvec8*)&Ks[cur][(r * 16 + (cd ^ (r & 7))) * 8];
            s0 = mfma16(qf0[ks], kf, s0);
            s1 = mfma16(qf1[ks], kf, s1);
          }
          sa0[fn] = s0; sa1[fn] = s1;
        }
        __builtin_amdgcn_s_setprio(0);

        smax(sa0, mr0, lr0, oacc0, q0w,      k0, (k0 + 63) > q0w,        0);
        smax(sa1, mr1, lr1, oacc1, q0w + 16, k0, (k0 + 63) > (q0w + 16), 1024);
      }

      // pre-PV: V(cur) landed when only the 16 newer loads (next tile's K+V) remain
      if (more) {
        asm volatile("s_waitcnt vmcnt(16)" ::: "memory");
      } else {
        asm volatile("s_waitcnt vmcnt(0)" ::: "memory");
      }
      __builtin_amdgcn_sched_barrier(0);
      __builtin_amdgcn_s_barrier();
      __builtin_amdgcn_sched_barrier(0);

      if (active) {
        // O += P V: 32 MFMAs sharing 16 V-frag reads
        __builtin_amdgcn_s_setprio(1);
#pragma unroll
        for (int ks2 = 0; ks2 < 2; ks2++) {
          bvec8 pf0 = *(const bvec8*)&Ps[wid][(lo * 8 + ((ks2 * 4 + gl) ^ (lo & 7))) * 8];
          bvec8 pf1 = *(const bvec8*)&Ps[wid][1024 + (lo * 8 + ((ks2 * 4 + gl) ^ (lo & 7))) * 8];
#pragma unroll
          for (int fd = 0; fd < 8; fd++) {
            bvec8 vf = *(const bvec8*)&Vs[cur][((ks2 * 4 + gl) * 128 + fd * 16 + lo) * 8];
            oacc0[fd] = mfma16(pf0, vf, oacc0[fd]);
            oacc1[fd] = mfma16(pf1, vf, oacc1[fd]);
          }
        }
        __builtin_amdgcn_s_setprio(0);
      }

      // end-of-tile: K(it+1) landed when only the 8 newer V-loads remain
      if (more) {
        asm volatile("s_waitcnt vmcnt(8)" ::: "memory");
      } else {
        asm volatile("s_waitcnt vmcnt(0)" ::: "memory");
      }
      __builtin_amdgcn_sched_barrier(0);
      __builtin_amdgcn_s_barrier();
      __builtin_amdgcn_sched_barrier(0);
    }

    // epilogue
#pragma unroll
    for (int r = 0; r < 4; r++) {
      float l0 = lr0[r], l1 = lr1[r];
#pragma unroll
      for (int dlt = 1; dlt < 16; dlt <<= 1) {
        l0 += __shfl_xor(l0, dlt);
        l1 += __shfl_xor(l1, dlt);
      }
      int qrow0 = q0w + gl * 4 + r;
      int qrow1 = q0w + 16 + gl * 4 + r;
      float inv0 = 1.f / l0, inv1 = 1.f / l1;
#pragma unroll
      for (int fd = 0; fd < 8; fd++) {
        int d = fd * 16 + lo;
        yb[((size_t)b * TT + qrow0) * CC + h * DD + d] = f2bf(oacc0[fd][r] * inv0);
        yb[((size_t)b * TT + qrow1) * CC + h * DD + d] = f2bf(oacc1[fd][r] * inv1);
      }
    }
  }
}

extern "C" void kernel_launch(void* const* d_in, const int* in_sizes, int n_in,
                              void* d_out, int out_size, void* d_ws, size_t ws_size,
                              hipStream_t stream) {
  const float* x      = (const float*)d_in[0];
  const float* w_attn = (const float*)d_in[1];
  const float* b_attn = (const float*)d_in[2];
  const float* w_proj = (const float*)d_in[3];
  const float* b_proj = (const float*)d_in[4];
  float* out = (float*)d_out;

  char* ws = (char*)d_ws;
  unsigned short* xb    = (unsigned short*)(ws);                         // 32 MB
  unsigned short* wab_t = (unsigned short*)(ws + 33554432);              // 24 MB
  unsigned short* wpb_t = (unsigned short*)(ws + 58720256);              // 8 MB
  unsigned short* qkws  = (unsigned short*)(ws + 67108864);              // 64 MB
  unsigned short* vtws  = (unsigned short*)(ws + 134217728);             // 32 MB
  unsigned short* ybws  = (unsigned short*)(ws + 167772160);             // 32 MB

  hipLaunchKernelGGL(k_prep, dim3(16384 + 3072 + 1024), dim3(256), 0, stream,
                     x, xb, w_attn, wab_t, w_proj, wpb_t);
  hipLaunchKernelGGL((k_gemm8<0>), dim3(24, 32), dim3(512), 0, stream,
                     xb, wab_t, b_attn, qkws, vtws, (float*)nullptr);
  hipLaunchKernelGGL(k_attn, dim3(512), dim3(256), 0, stream, qkws, vtws, ybws);
  hipLaunchKernelGGL((k_gemm8<1>), dim3(8, 32), dim3(512), 0, stream,
                     ybws, wpb_t, b_proj, (unsigned short*)nullptr, (unsigned short*)nullptr, out);
}